// Round 1
// baseline (8499.434 us; speedup 1.0000x reference)
//
#include <hip/hip_runtime.h>
#include <cstdint>
#include <cstddef>

#define H   500
#define G3  1500
#define SEQ 512
#define V   50000
#define NT  391          // ceil(50000/128)

// ---------------- workspace layout (bytes) ----------------
static constexpr size_t OFS_CTR    = 0;                          // 2 counters (offset 0 and 64B)
static constexpr size_t OFS_HBUF   = 1024;                       // 2*512 f32 ping-pong h
static constexpr size_t OFS_ENCH   = 8192;                       // 512 f32 final encoder h
static constexpr size_t OFS_GI_ENC = 16384;                      // 512*1500 f32
static constexpr size_t OFS_GI_DEC = OFS_GI_ENC + 3276800;
static constexpr size_t OFS_DECHS  = OFS_GI_DEC + 3276800;       // 512*500 f32
static constexpr size_t OFS_SPART  = OFS_DECHS + 1572864;        // 512*NT f32
static constexpr size_t OFS_PPART  = OFS_SPART + 1048576;        // 512*NT u64
static constexpr size_t OFS_LTGT   = OFS_PPART + 2097152;        // 512 f32
static constexpr size_t OFS_SFIN   = OFS_LTGT + 4096;            // 512 f32

__global__ __launch_bounds__(64) void k_init(unsigned* ctr) {
    if (threadIdx.x < 2) ctr[threadIdx.x * 16] = 0u;   // ctr_enc @0, ctr_dec @64B
}

// ---------------- input-gate GEMM: Gi = gather(emb)@Wih.T + bih ----------------
#define GI_BM 64
#define GI_BN 64
#define GI_BK 20
__global__ __launch_bounds__(256) void k_gi_gemm(
    const float* __restrict__ emb, const float* __restrict__ Wih,
    const float* __restrict__ bih, const int* __restrict__ toks,
    int dec_mode, float* __restrict__ Gi)
{
    __shared__ __align__(16) float As[GI_BK * GI_BM];
    __shared__ __align__(16) float Bs[GI_BK * GI_BN];
    const int tid = threadIdx.x;
    const int n0 = blockIdx.x * GI_BN;
    const int m0 = blockIdx.y * GI_BM;
    const int tx = tid & 15, ty = tid >> 4;
    float acc[4][4] = {};
    for (int k0 = 0; k0 < H; k0 += GI_BK) {
        for (int x = tid; x < GI_BM * GI_BK; x += 256) {
            int m = x / GI_BK, k = x - m * GI_BK;
            int gm = m0 + m;
            int tok;
            float v;
            if (dec_mode) {
                tok = (gm == 0) ? 0 : toks[gm - 1];
                v = emb[(size_t)tok * H + k0 + k];
                v = v > 0.f ? v : 0.f;               // relu(dec_emb[...])
            } else {
                tok = toks[gm];
                v = emb[(size_t)tok * H + k0 + k];
            }
            As[k * GI_BM + m] = v;
        }
        for (int x = tid; x < GI_BN * GI_BK; x += 256) {
            int n = x / GI_BK, k = x - n * GI_BK;
            int gn = n0 + n;
            Bs[k * GI_BN + n] = (gn < G3) ? Wih[(size_t)gn * H + k0 + k] : 0.f;
        }
        __syncthreads();
#pragma unroll 5
        for (int kk = 0; kk < GI_BK; ++kk) {
            float a[4], b[4];
            *(float4*)&a[0] = *(const float4*)&As[kk * GI_BM + ty * 4];
            *(float4*)&b[0] = *(const float4*)&Bs[kk * GI_BN + tx * 4];
#pragma unroll
            for (int i = 0; i < 4; i++)
#pragma unroll
                for (int j = 0; j < 4; j++) acc[i][j] = fmaf(a[i], b[j], acc[i][j]);
        }
        __syncthreads();
    }
#pragma unroll
    for (int i = 0; i < 4; i++) {
        int gm = m0 + ty * 4 + i;
#pragma unroll
        for (int j = 0; j < 4; j++) {
            int gn = n0 + tx * 4 + j;
            if (gn < G3) Gi[(size_t)gm * G3 + gn] = acc[i][j] + bih[gn];
        }
    }
}

// ---------------- persistent GRU scan (20 co-resident WGs, 1 barrier/step) ----------------
#define NB  20
#define HSL 25   // h slice per WG
__global__ __launch_bounds__(256) void k_gru(
    const float* __restrict__ Whh, const float* __restrict__ bhh,
    const float* __restrict__ Gi, const float* __restrict__ h0,
    float* hbuf, float* hfinal, float* hs_out, float* douth,
    unsigned* ctr, int S)
{
    __shared__ float h_s[H];
    __shared__ float gh_s[3 * HSL];
    const int tid = threadIdx.x;
    const int j0 = blockIdx.x * HSL;
    for (int t = 0; t < S; ++t) {
        const float* hsrc = (t == 0) ? h0 : (hbuf + ((t - 1) & 1) * 512);
        for (int i = tid; i < H; i += 256)
            h_s[i] = __hip_atomic_load(hsrc + i, __ATOMIC_RELAXED, __HIP_MEMORY_SCOPE_AGENT);
        __syncthreads();
        if (tid < 150) {                              // 75 rows x 2 half-dots
            const int rl = tid >> 1, half = tid & 1;
            const int gate = rl / HSL, jl = rl - gate * HSL;
            const int row = gate * 500 + j0 + jl;
            const float2* wr = (const float2*)(Whh + (size_t)row * H) + half * 125;
            const float2* hv = (const float2*)h_s + half * 125;
            float s = 0.f;
#pragma unroll 5
            for (int k = 0; k < 125; ++k) {
                float2 w = wr[k], x = hv[k];
                s = fmaf(w.x, x.x, s);
                s = fmaf(w.y, x.y, s);
            }
            s += __shfl_xor(s, 1);
            if (!half) gh_s[gate * HSL + jl] = s + bhh[row];
        }
        __syncthreads();
        if (tid < HSL) {
            const int j = j0 + tid;
            const float* gi = Gi + (size_t)t * G3;
            const float hr = gh_s[tid], hz = gh_s[HSL + tid], hn = gh_s[2 * HSL + tid];
            const float ir = gi[j], iz = gi[500 + j], inn = gi[1000 + j];
            const float r = 1.f / (1.f + __expf(-(ir + hr)));
            const float z = 1.f / (1.f + __expf(-(iz + hz)));
            const float n = tanhf(inn + r * hn);
            const float hnew = (1.f - z) * n + z * h_s[j];
            __hip_atomic_store(hbuf + (t & 1) * 512 + j, hnew, __ATOMIC_RELAXED, __HIP_MEMORY_SCOPE_AGENT);
            if (hs_out) hs_out[(size_t)t * H + j] = hnew;
            if (t == S - 1) {
                if (hfinal) __hip_atomic_store(hfinal + j, hnew, __ATOMIC_RELAXED, __HIP_MEMORY_SCOPE_AGENT);
                if (douth) douth[j] = hnew;
            }
        }
        __threadfence();
        __syncthreads();
        if (tid == 0) {
            __hip_atomic_fetch_add(ctr, 1u, __ATOMIC_ACQ_REL, __HIP_MEMORY_SCOPE_AGENT);
            const unsigned goal = (unsigned)gridDim.x * (unsigned)(t + 1);
            while (__hip_atomic_load(ctr, __ATOMIC_RELAXED, __HIP_MEMORY_SCOPE_AGENT) < goal) {}
            __threadfence();
        }
        __syncthreads();
    }
}

// ---------------- logits GEMM with fused sum-exp / argmax partials ----------------
#define LG_BM 128
#define LG_BN 128
#define LG_BK 20
__global__ __launch_bounds__(256) void k_logits(
    const float* __restrict__ A, const float* __restrict__ Bw,
    const float* __restrict__ bias,
    float* __restrict__ S_part, unsigned long long* __restrict__ P_part)
{
    __shared__ __align__(16) float As[LG_BK * LG_BM];
    __shared__ __align__(16) float Bs[LG_BK * LG_BN];
    const int tid = threadIdx.x;
    const int bx = blockIdx.x;
    const int n0 = bx * LG_BN;
    const int m0 = blockIdx.y * LG_BM;
    const int tx = tid & 15, ty = tid >> 4;
    float acc[8][8] = {};
    for (int k0 = 0; k0 < H; k0 += LG_BK) {
        for (int x = tid; x < LG_BM * LG_BK; x += 256) {
            int m = x / LG_BK, k = x - m * LG_BK;
            As[k * LG_BM + m] = A[(size_t)(m0 + m) * H + k0 + k];
        }
        for (int x = tid; x < LG_BN * LG_BK; x += 256) {
            int n = x / LG_BK, k = x - n * LG_BK;
            int gn = n0 + n;
            Bs[k * LG_BN + n] = (gn < V) ? Bw[(size_t)gn * H + k0 + k] : 0.f;
        }
        __syncthreads();
#pragma unroll 5
        for (int kk = 0; kk < LG_BK; ++kk) {
            float a[8], b[8];
            *(float4*)&a[0] = *(const float4*)&As[kk * LG_BM + ty * 8];
            *(float4*)&a[4] = *(const float4*)&As[kk * LG_BM + ty * 8 + 4];
            *(float4*)&b[0] = *(const float4*)&Bs[kk * LG_BN + tx * 8];
            *(float4*)&b[4] = *(const float4*)&Bs[kk * LG_BN + tx * 8 + 4];
#pragma unroll
            for (int i = 0; i < 8; i++)
#pragma unroll
                for (int j = 0; j < 8; j++) acc[i][j] = fmaf(a[i], b[j], acc[i][j]);
        }
        __syncthreads();
    }
    // fused epilogue: per-row partial sumexp + packed max|~idx  (no max-sub needed: |logit|<~1)
    float bcol[8]; int gncol[8]; bool bval[8];
#pragma unroll
    for (int j = 0; j < 8; j++) {
        int gn = n0 + tx * 8 + j;
        gncol[j] = gn; bval[j] = gn < V; bcol[j] = bval[j] ? bias[gn] : 0.f;
    }
#pragma unroll
    for (int i = 0; i < 8; i++) {
        int gm = m0 + ty * 8 + i;
        float mx = -3.4e38f; unsigned mi = 0; float se = 0.f;
#pragma unroll
        for (int j = 0; j < 8; j++) {
            if (bval[j]) {
                float l = acc[i][j] + bcol[j];
                se += __expf(l);
                if (l > mx) { mx = l; mi = (unsigned)gncol[j]; }
            }
        }
        unsigned u = __float_as_uint(mx);
        unsigned key = (u & 0x80000000u) ? ~u : (u | 0x80000000u);
        unsigned long long pk = ((unsigned long long)key << 32) |
                                (unsigned long long)(0xFFFFFFFFu - mi);   // ~idx: ties -> lowest idx (numpy)
#pragma unroll
        for (int off = 1; off < 16; off <<= 1) {
            unsigned long long pk2 = __shfl_xor(pk, off);
            se += __shfl_xor(se, off);
            if (pk2 > pk) pk = pk2;
        }
        if (tx == 0) {
            S_part[(size_t)gm * NT + bx] = se;
            P_part[(size_t)gm * NT + bx] = pk;
        }
    }
}

__global__ __launch_bounds__(128) void k_reduce_rows(
    const float* __restrict__ S_part, const unsigned long long* __restrict__ P_part,
    float* __restrict__ Sfin, float* __restrict__ out_argmax)
{
    const int row = blockIdx.x, tid = threadIdx.x;
    float s = 0.f; unsigned long long p = 0ull;
    for (int i = tid; i < NT; i += 128) {
        s += S_part[(size_t)row * NT + i];
        unsigned long long q = P_part[(size_t)row * NT + i];
        if (q > p) p = q;
    }
#pragma unroll
    for (int off = 1; off < 64; off <<= 1) {
        s += __shfl_xor(s, off);
        unsigned long long q = __shfl_xor(p, off);
        if (q > p) p = q;
    }
    __shared__ float s2[2];
    __shared__ unsigned long long p2[2];
    if ((tid & 63) == 0) { s2[tid >> 6] = s; p2[tid >> 6] = p; }
    __syncthreads();
    if (tid == 0) {
        s = s2[0] + s2[1];
        p = p2[0] > p2[1] ? p2[0] : p2[1];
        Sfin[row] = s;
        unsigned idx = 0xFFFFFFFFu - (unsigned)(p & 0xFFFFFFFFull);
        out_argmax[row] = (float)idx;
    }
}

__global__ __launch_bounds__(64) void k_ltgt(
    const float* __restrict__ A, const float* __restrict__ Bw,
    const float* __restrict__ bias, const int* __restrict__ tgt,
    float* __restrict__ ltgt)
{
    const int row = blockIdx.x, lane = threadIdx.x;
    const int tok = tgt[row];
    const float* a = A + (size_t)row * H;
    const float* b = Bw + (size_t)tok * H;
    float s = 0.f;
    for (int k = lane; k < H; k += 64) s = fmaf(a[k], b[k], s);
#pragma unroll
    for (int off = 1; off < 64; off <<= 1) s += __shfl_xor(s, off);
    if (lane == 0) ltgt[row] = s + bias[tok];
}

__global__ __launch_bounds__(512) void k_final(
    const float* __restrict__ Sfin, const float* __restrict__ ltgt, float* __restrict__ d_out)
{
    __shared__ float red[512];
    const int t = threadIdx.x;
    red[t] = logf(Sfin[t]) - ltgt[t];
    __syncthreads();
    for (int s = 256; s > 0; s >>= 1) {
        if (t < s) red[t] += red[t + s];
        __syncthreads();
    }
    if (t == 0) d_out[0] = red[0];
}

extern "C" void kernel_launch(void* const* d_in, const int* in_sizes, int n_in,
                              void* d_out, int out_size, void* d_ws, size_t ws_size,
                              hipStream_t stream) {
    const int*   enc_ids = (const int*)d_in[0];
    const int*   tgt     = (const int*)d_in[1];
    const float* enc_h0  = (const float*)d_in[2];
    const float* enc_emb = (const float*)d_in[3];
    const float* enc_Wih = (const float*)d_in[4];
    const float* enc_Whh = (const float*)d_in[5];
    const float* enc_bih = (const float*)d_in[6];
    const float* enc_bhh = (const float*)d_in[7];
    const float* dec_emb = (const float*)d_in[8];
    const float* dec_Wih = (const float*)d_in[9];
    const float* dec_Whh = (const float*)d_in[10];
    const float* dec_bih = (const float*)d_in[11];
    const float* dec_bhh = (const float*)d_in[12];
    const float* out_W   = (const float*)d_in[13];
    const float* out_b   = (const float*)d_in[14];
    float* out = (float*)d_out;

    char* ws = (char*)d_ws;
    unsigned* ctr = (unsigned*)(ws + OFS_CTR);
    float* hbuf   = (float*)(ws + OFS_HBUF);
    float* ench   = (float*)(ws + OFS_ENCH);
    float* gi_enc = (float*)(ws + OFS_GI_ENC);
    float* gi_dec = (float*)(ws + OFS_GI_DEC);
    float* dechs  = (float*)(ws + OFS_DECHS);
    float* Spart  = (float*)(ws + OFS_SPART);
    unsigned long long* Ppart = (unsigned long long*)(ws + OFS_PPART);
    float* ltgt   = (float*)(ws + OFS_LTGT);
    float* Sfin   = (float*)(ws + OFS_SFIN);

    k_init<<<dim3(1), dim3(64), 0, stream>>>(ctr);
    dim3 gi_grid(24, 8);
    k_gi_gemm<<<gi_grid, dim3(256), 0, stream>>>(enc_emb, enc_Wih, enc_bih, enc_ids, 0, gi_enc);
    k_gi_gemm<<<gi_grid, dim3(256), 0, stream>>>(dec_emb, dec_Wih, dec_bih, tgt, 1, gi_dec);
    k_gru<<<dim3(NB), dim3(256), 0, stream>>>(enc_Whh, enc_bhh, gi_enc, enc_h0,
                                              hbuf, ench, (float*)nullptr, out + 1, ctr, SEQ);
    k_gru<<<dim3(NB), dim3(256), 0, stream>>>(dec_Whh, dec_bhh, gi_dec, ench,
                                              hbuf, (float*)nullptr, dechs, (float*)nullptr, ctr + 16, SEQ);
    k_ltgt<<<dim3(SEQ), dim3(64), 0, stream>>>(dechs, out_W, out_b, tgt, ltgt);
    k_logits<<<dim3(NT, 4), dim3(256), 0, stream>>>(dechs, out_W, out_b, Spart, Ppart);
    k_reduce_rows<<<dim3(SEQ), dim3(128), 0, stream>>>(Spart, Ppart, Sfin, out + 1 + H);
    k_final<<<dim3(1), dim3(512), 0, stream>>>(Sfin, ltgt, out);
}

// Round 3
// 6176.009 us; speedup vs baseline: 1.3762x; 1.3762x over previous
//
#include <hip/hip_runtime.h>
#include <cstdint>
#include <cstddef>

#define H    500
#define G3   1500
#define SEQ  512
#define V    50000
#define NT   391          // ceil(50000/128)

#define NB   25           // GRU workgroups; HSL = 20 h-elements per WG
#define HSL  20
#define ROWS 60           // 3 gates x 20 rows per WG

// ---------------- workspace layout (bytes) ----------------
// hbuf: [2 bufs][25 slices][32 u64] tagged pairs (tag<<32 | f32 bits); slice stride 256B
static constexpr size_t OFS_HBUF_E = 0;            // 12800 B
static constexpr size_t OFS_HBUF_D = 16384;        // 12800 B
static constexpr size_t OFS_ENCH   = 32768;        // 500 f32
static constexpr size_t OFS_GI_ENC = 65536;        // 512*1500 f32
static constexpr size_t OFS_GI_DEC = OFS_GI_ENC + 3276800;
static constexpr size_t OFS_DECHS  = OFS_GI_DEC + 3276800;   // 512*500 f32
static constexpr size_t OFS_SPART  = OFS_DECHS + 1048576;    // 512*NT f32
static constexpr size_t OFS_PPART  = OFS_SPART + 1048576;    // 512*NT u64
static constexpr size_t OFS_LTGT   = OFS_PPART + 2097152;    // 512 f32
static constexpr size_t OFS_SFIN   = OFS_LTGT + 4096;        // 512 f32

// ---------------- input-gate GEMM: Gi = gather(emb)@Wih.T + bih (enc z=0, dec z=1) ----------------
#define GI_BM 64
#define GI_BN 64
#define GI_BK 20
__global__ __launch_bounds__(256) void k_gi_gemm(
    const float* __restrict__ eA, const float* __restrict__ WA,
    const float* __restrict__ bA, const int* __restrict__ tA,
    const float* __restrict__ eB, const float* __restrict__ WB,
    const float* __restrict__ bB, const int* __restrict__ tB,
    float* __restrict__ GiA, float* __restrict__ GiB)
{
    const int dec = blockIdx.z;
    const float* emb = dec ? eB : eA;
    const float* Wih = dec ? WB : WA;
    const float* bih = dec ? bB : bA;
    const int*  toks = dec ? tB : tA;
    float* Gi        = dec ? GiB : GiA;

    __shared__ __align__(16) float As[GI_BK * GI_BM];
    __shared__ __align__(16) float Bs[GI_BK * GI_BN];
    const int tid = threadIdx.x;
    const int n0 = blockIdx.x * GI_BN;
    const int m0 = blockIdx.y * GI_BM;
    const int tx = tid & 15, ty = tid >> 4;
    float acc[4][4] = {};
    for (int k0 = 0; k0 < H; k0 += GI_BK) {
        for (int x = tid; x < 320; x += 256) {        // 64 rows x 5 float4
            int m = x / 5, kq = x - m * 5;
            int gm = m0 + m;
            int tok = dec ? ((gm == 0) ? 0 : toks[gm - 1]) : toks[gm];
            float4 v = *(const float4*)(emb + (size_t)tok * H + k0 + kq * 4);
            if (dec) { v.x = fmaxf(v.x, 0.f); v.y = fmaxf(v.y, 0.f);
                       v.z = fmaxf(v.z, 0.f); v.w = fmaxf(v.w, 0.f); }
            int kb = kq * 4;
            As[(kb + 0) * GI_BM + m] = v.x; As[(kb + 1) * GI_BM + m] = v.y;
            As[(kb + 2) * GI_BM + m] = v.z; As[(kb + 3) * GI_BM + m] = v.w;
        }
        for (int x = tid; x < 320; x += 256) {
            int n = x / 5, kq = x - n * 5;
            int gn = n0 + n;
            float4 v = make_float4(0.f, 0.f, 0.f, 0.f);
            if (gn < G3) v = *(const float4*)(Wih + (size_t)gn * H + k0 + kq * 4);
            int kb = kq * 4;
            Bs[(kb + 0) * GI_BN + n] = v.x; Bs[(kb + 1) * GI_BN + n] = v.y;
            Bs[(kb + 2) * GI_BN + n] = v.z; Bs[(kb + 3) * GI_BN + n] = v.w;
        }
        __syncthreads();
#pragma unroll 5
        for (int kk = 0; kk < GI_BK; ++kk) {
            float a[4], b[4];
            *(float4*)&a[0] = *(const float4*)&As[kk * GI_BM + ty * 4];
            *(float4*)&b[0] = *(const float4*)&Bs[kk * GI_BN + tx * 4];
#pragma unroll
            for (int i = 0; i < 4; i++)
#pragma unroll
                for (int j = 0; j < 4; j++) acc[i][j] = fmaf(a[i], b[j], acc[i][j]);
        }
        __syncthreads();
    }
#pragma unroll
    for (int i = 0; i < 4; i++) {
        int gm = m0 + ty * 4 + i;
#pragma unroll
        for (int j = 0; j < 4; j++) {
            int gn = n0 + tx * 4 + j;
            if (gn < G3) Gi[(size_t)gm * G3 + gn] = acc[i][j] + bih[gn];
        }
    }
}

// ---------------- persistent GRU scan: tagged-pair dataflow, W in VGPRs ----------------
// Mapping: tid<250 -> g=tid/25 (rowgroup, 6 rows), s=tid%25 (k-segment of 20).
// Full k-coverage: 25 segments x 20 = 500.  (Round-2 bug: only 20 segments = 400.)
__global__ __launch_bounds__(256, 1) void k_gru(
    const float* __restrict__ Whh, const float* __restrict__ bhh,
    const float* __restrict__ Gi, const float* __restrict__ h0,
    unsigned long long* hbuf, float* hfinal, float* hs_out, float* douth, int S)
{
    __shared__ float p_s[ROWS * 26];   // partials, stride 26 breaks bank conflicts
    __shared__ float gh_s[ROWS];
    const int tid = threadIdx.x;
    const int wg = blockIdx.x;
    const int j0 = wg * HSL;

    const int g = tid / 25;            // 0..9  (tid<250)
    const int s = tid - g * 25;        // 0..24

    // ---- preload W rows into registers (120 VGPRs/lane) ----
    float wreg[6][20];
    if (tid < 250) {
#pragma unroll
        for (int r = 0; r < 6; ++r) {
            const int rl = g * 6 + r;                    // 0..59
            const int gate = rl / 20, jl = rl - gate * 20;
            const float* wr = Whh + (size_t)(gate * 500 + j0 + jl) * H + s * 20;
#pragma unroll
            for (int c = 0; c < 5; ++c)
                *(float4*)&wreg[r][c * 4] = *(const float4*)(wr + c * 4);
        }
    }
    float bb = 0.f;
    if (tid < ROWS) {
        const int gate = tid / 20, jl = tid - gate * 20;
        bb = bhh[gate * 500 + j0 + jl];
    }
    // own h slice lives in a register of lanes tid<HSL
    float hown = (tid < HSL) ? h0[j0 + tid] : 0.f;

    // ---- prestage h0 into buf1 with tag 1 ----
    if (tid < HSL)
        __hip_atomic_store(hbuf + 800 + wg * 32 + tid,
                           ((unsigned long long)1u << 32) | (unsigned)__float_as_uint(hown),
                           __ATOMIC_RELAXED, __HIP_MEMORY_SCOPE_AGENT);

    for (int t = 0; t < S; ++t) {
        const unsigned want = (unsigned)(t + 1);
        const int rb = (t + 1) & 1;                      // read buffer
        // Gi prefetch (long-latency, overlaps the retry wait)
        float ir = 0.f, iz = 0.f, inn = 0.f;
        if (tid < HSL) {
            const float* gi = Gi + (size_t)t * G3 + j0 + tid;
            ir = gi[0]; iz = gi[500]; inn = gi[1000];
        }
        // ---- retry-load h segment s (20 tagged pairs) until all tags match ----
        float acc[6] = {0.f, 0.f, 0.f, 0.f, 0.f, 0.f};
        if (tid < 250) {
            const unsigned long long* base = hbuf + rb * 800 + s * 32;
            unsigned long long pv[20];
            bool ok;
            do {
                ok = true;
#pragma unroll
                for (int i = 0; i < 20; ++i)
                    pv[i] = __hip_atomic_load(base + i, __ATOMIC_RELAXED, __HIP_MEMORY_SCOPE_AGENT);
#pragma unroll
                for (int i = 0; i < 20; ++i)
                    ok = ok && ((unsigned)(pv[i] >> 32) == want);
            } while (!ok);
            // ---- dot: 120 FMAs, W from registers ----
#pragma unroll
            for (int i = 0; i < 20; ++i) {
                const float hv = __uint_as_float((unsigned)pv[i]);
#pragma unroll
                for (int r = 0; r < 6; ++r) acc[r] = fmaf(wreg[r][i], hv, acc[r]);
            }
#pragma unroll
            for (int r = 0; r < 6; ++r) p_s[(g * 6 + r) * 26 + s] = acc[r];
        }
        __syncthreads();
        // ---- row reduction over the 25 k-segments ----
        if (tid < ROWS) {
            float sum = 0.f;
#pragma unroll 5
            for (int i = 0; i < 25; ++i) sum += p_s[tid * 26 + i];
            gh_s[tid] = sum + bb;
        }
        __syncthreads();
        // ---- GRU update for own slice ----
        if (tid < HSL) {
            const int j = j0 + tid;
            const float hr = gh_s[tid], hz = gh_s[HSL + tid], hn = gh_s[2 * HSL + tid];
            const float r = 1.f / (1.f + __expf(-(ir + hr)));
            const float z = 1.f / (1.f + __expf(-(iz + hz)));
            const float n = tanhf(inn + r * hn);
            const float hnew = (1.f - z) * n + z * hown;
            hown = hnew;
            __hip_atomic_store(hbuf + (t & 1) * 800 + wg * 32 + tid,
                               ((unsigned long long)(unsigned)(t + 2) << 32) |
                               (unsigned)__float_as_uint(hnew),
                               __ATOMIC_RELAXED, __HIP_MEMORY_SCOPE_AGENT);
            if (hs_out) hs_out[(size_t)t * H + j] = hnew;
            if (t == S - 1) {
                if (hfinal) hfinal[j] = hnew;
                if (douth)  douth[j]  = hnew;
            }
        }
        // no barrier needed here: next step's p_s writes are gated by the first barrier
    }
}

// ---------------- logits GEMM with fused sum-exp / argmax partials ----------------
#define LG_BM 128
#define LG_BN 128
#define LG_BK 20
__global__ __launch_bounds__(256) void k_logits(
    const float* __restrict__ A, const float* __restrict__ Bw,
    const float* __restrict__ bias,
    float* __restrict__ S_part, unsigned long long* __restrict__ P_part)
{
    __shared__ __align__(16) float As[LG_BK * LG_BM];
    __shared__ __align__(16) float Bs[LG_BK * LG_BN];
    const int tid = threadIdx.x;
    const int bx = blockIdx.x;
    const int n0 = bx * LG_BN;
    const int m0 = blockIdx.y * LG_BM;
    const int tx = tid & 15, ty = tid >> 4;
    float acc[8][8] = {};
    for (int k0 = 0; k0 < H; k0 += LG_BK) {
        for (int x = tid; x < LG_BM * LG_BK; x += 256) {
            int m = x / LG_BK, k = x - m * LG_BK;
            As[k * LG_BM + m] = A[(size_t)(m0 + m) * H + k0 + k];
        }
        for (int x = tid; x < LG_BN * LG_BK; x += 256) {
            int n = x / LG_BK, k = x - n * LG_BK;
            int gn = n0 + n;
            Bs[k * LG_BN + n] = (gn < V) ? Bw[(size_t)gn * H + k0 + k] : 0.f;
        }
        __syncthreads();
#pragma unroll 5
        for (int kk = 0; kk < LG_BK; ++kk) {
            float a[8], b[8];
            *(float4*)&a[0] = *(const float4*)&As[kk * LG_BM + ty * 8];
            *(float4*)&a[4] = *(const float4*)&As[kk * LG_BM + ty * 8 + 4];
            *(float4*)&b[0] = *(const float4*)&Bs[kk * LG_BN + tx * 8];
            *(float4*)&b[4] = *(const float4*)&Bs[kk * LG_BN + tx * 8 + 4];
#pragma unroll
            for (int i = 0; i < 8; i++)
#pragma unroll
                for (int j = 0; j < 8; j++) acc[i][j] = fmaf(a[i], b[j], acc[i][j]);
        }
        __syncthreads();
    }
    float bcol[8]; int gncol[8]; bool bval[8];
#pragma unroll
    for (int j = 0; j < 8; j++) {
        int gn = n0 + tx * 8 + j;
        gncol[j] = gn; bval[j] = gn < V; bcol[j] = bval[j] ? bias[gn] : 0.f;
    }
#pragma unroll
    for (int i = 0; i < 8; i++) {
        int gm = m0 + ty * 8 + i;
        float mx = -3.4e38f; unsigned mi = 0; float se = 0.f;
#pragma unroll
        for (int j = 0; j < 8; j++) {
            if (bval[j]) {
                float l = acc[i][j] + bcol[j];
                se += __expf(l);
                if (l > mx) { mx = l; mi = (unsigned)gncol[j]; }
            }
        }
        unsigned u = __float_as_uint(mx);
        unsigned key = (u & 0x80000000u) ? ~u : (u | 0x80000000u);
        unsigned long long pk = ((unsigned long long)key << 32) |
                                (unsigned long long)(0xFFFFFFFFu - mi);
#pragma unroll
        for (int off = 1; off < 16; off <<= 1) {
            unsigned long long pk2 = __shfl_xor(pk, off);
            se += __shfl_xor(se, off);
            if (pk2 > pk) pk = pk2;
        }
        if (tx == 0) {
            S_part[(size_t)gm * NT + bx] = se;
            P_part[(size_t)gm * NT + bx] = pk;
        }
    }
}

__global__ __launch_bounds__(128) void k_reduce_rows(
    const float* __restrict__ S_part, const unsigned long long* __restrict__ P_part,
    float* __restrict__ Sfin, float* __restrict__ out_argmax)
{
    const int row = blockIdx.x, tid = threadIdx.x;
    float s = 0.f; unsigned long long p = 0ull;
    for (int i = tid; i < NT; i += 128) {
        s += S_part[(size_t)row * NT + i];
        unsigned long long q = P_part[(size_t)row * NT + i];
        if (q > p) p = q;
    }
#pragma unroll
    for (int off = 1; off < 64; off <<= 1) {
        s += __shfl_xor(s, off);
        unsigned long long q = __shfl_xor(p, off);
        if (q > p) p = q;
    }
    __shared__ float s2[2];
    __shared__ unsigned long long p2[2];
    if ((tid & 63) == 0) { s2[tid >> 6] = s; p2[tid >> 6] = p; }
    __syncthreads();
    if (tid == 0) {
        s = s2[0] + s2[1];
        p = p2[0] > p2[1] ? p2[0] : p2[1];
        Sfin[row] = s;
        unsigned idx = 0xFFFFFFFFu - (unsigned)(p & 0xFFFFFFFFull);
        out_argmax[row] = (float)idx;
    }
}

__global__ __launch_bounds__(64) void k_ltgt(
    const float* __restrict__ A, const float* __restrict__ Bw,
    const float* __restrict__ bias, const int* __restrict__ tgt,
    float* __restrict__ ltgt)
{
    const int row = blockIdx.x, lane = threadIdx.x;
    const int tok = tgt[row];
    const float* a = A + (size_t)row * H;
    const float* b = Bw + (size_t)tok * H;
    float s = 0.f;
    for (int k = lane; k < H; k += 64) s = fmaf(a[k], b[k], s);
#pragma unroll
    for (int off = 1; off < 64; off <<= 1) s += __shfl_xor(s, off);
    if (lane == 0) ltgt[row] = s + bias[tok];
}

__global__ __launch_bounds__(512) void k_final(
    const float* __restrict__ Sfin, const float* __restrict__ ltgt, float* __restrict__ d_out)
{
    __shared__ float red[512];
    const int t = threadIdx.x;
    red[t] = logf(Sfin[t]) - ltgt[t];
    __syncthreads();
    for (int s = 256; s > 0; s >>= 1) {
        if (t < s) red[t] += red[t + s];
        __syncthreads();
    }
    if (t == 0) d_out[0] = red[0];
}

extern "C" void kernel_launch(void* const* d_in, const int* in_sizes, int n_in,
                              void* d_out, int out_size, void* d_ws, size_t ws_size,
                              hipStream_t stream) {
    const int*   enc_ids = (const int*)d_in[0];
    const int*   tgt     = (const int*)d_in[1];
    const float* enc_h0  = (const float*)d_in[2];
    const float* enc_emb = (const float*)d_in[3];
    const float* enc_Wih = (const float*)d_in[4];
    const float* enc_Whh = (const float*)d_in[5];
    const float* enc_bih = (const float*)d_in[6];
    const float* enc_bhh = (const float*)d_in[7];
    const float* dec_emb = (const float*)d_in[8];
    const float* dec_Wih = (const float*)d_in[9];
    const float* dec_Whh = (const float*)d_in[10];
    const float* dec_bih = (const float*)d_in[11];
    const float* dec_bhh = (const float*)d_in[12];
    const float* out_W   = (const float*)d_in[13];
    const float* out_b   = (const float*)d_in[14];
    float* out = (float*)d_out;

    char* ws = (char*)d_ws;
    unsigned long long* hbufE = (unsigned long long*)(ws + OFS_HBUF_E);
    unsigned long long* hbufD = (unsigned long long*)(ws + OFS_HBUF_D);
    float* ench   = (float*)(ws + OFS_ENCH);
    float* gi_enc = (float*)(ws + OFS_GI_ENC);
    float* gi_dec = (float*)(ws + OFS_GI_DEC);
    float* dechs  = (float*)(ws + OFS_DECHS);
    float* Spart  = (float*)(ws + OFS_SPART);
    unsigned long long* Ppart = (unsigned long long*)(ws + OFS_PPART);
    float* ltgt   = (float*)(ws + OFS_LTGT);
    float* Sfin   = (float*)(ws + OFS_SFIN);

    k_gi_gemm<<<dim3(24, 8, 2), dim3(256), 0, stream>>>(
        enc_emb, enc_Wih, enc_bih, enc_ids,
        dec_emb, dec_Wih, dec_bih, tgt, gi_enc, gi_dec);
    k_gru<<<dim3(NB), dim3(256), 0, stream>>>(enc_Whh, enc_bhh, gi_enc, enc_h0,
                                              hbufE, ench, (float*)nullptr, out + 1, SEQ);
    k_gru<<<dim3(NB), dim3(256), 0, stream>>>(dec_Whh, dec_bhh, gi_dec, ench,
                                              hbufD, (float*)nullptr, dechs, (float*)nullptr, SEQ);
    k_ltgt<<<dim3(SEQ), dim3(64), 0, stream>>>(dechs, out_W, out_b, tgt, ltgt);
    k_logits<<<dim3(NT, 4), dim3(256), 0, stream>>>(dechs, out_W, out_b, Spart, Ppart);
    k_reduce_rows<<<dim3(SEQ), dim3(128), 0, stream>>>(Spart, Ppart, Sfin, out + 1 + H);
    k_final<<<dim3(1), dim3(512), 0, stream>>>(Sfin, ltgt, out);
}

// Round 4
// 2570.663 us; speedup vs baseline: 3.3063x; 2.4025x over previous
//
#include <hip/hip_runtime.h>
#include <cstdint>
#include <cstddef>

#define H    500
#define G3   1500
#define SEQ  512
#define V    50000
#define NT   391          // ceil(50000/128)

#define NB   25           // GRU workgroups; HSL = 20 h-elements per WG
#define HSL  20
#define ROWS 60           // 3 gates x 20 rows per WG

// ---------------- workspace layout (bytes) ----------------
// hbuf: [2 bufs][25 slices][32 u64] tagged pairs (tag<<32 | f32 bits); slice stride 256B
static constexpr size_t OFS_HBUF_E = 0;            // 12800 B
static constexpr size_t OFS_HBUF_D = 16384;        // 12800 B
static constexpr size_t OFS_ENCH   = 32768;        // 500 f32
static constexpr size_t OFS_GI_ENC = 65536;        // 512*1500 f32
static constexpr size_t OFS_GI_DEC = OFS_GI_ENC + 3276800;
static constexpr size_t OFS_DECHS  = OFS_GI_DEC + 3276800;   // 512*500 f32
static constexpr size_t OFS_SPART  = OFS_DECHS + 1048576;    // 512*NT f32
static constexpr size_t OFS_PPART  = OFS_SPART + 1048576;    // 512*NT u64
static constexpr size_t OFS_LTGT   = OFS_PPART + 2097152;    // 512 f32
static constexpr size_t OFS_SFIN   = OFS_LTGT + 4096;        // 512 f32

// ---------------- input-gate GEMM: Gi = gather(emb)@Wih.T + bih (enc z=0, dec z=1) ----------------
#define GI_BM 64
#define GI_BN 64
#define GI_BK 20
__global__ __launch_bounds__(256) void k_gi_gemm(
    const float* __restrict__ eA, const float* __restrict__ WA,
    const float* __restrict__ bA, const int* __restrict__ tA,
    const float* __restrict__ eB, const float* __restrict__ WB,
    const float* __restrict__ bB, const int* __restrict__ tB,
    float* __restrict__ GiA, float* __restrict__ GiB)
{
    const int dec = blockIdx.z;
    const float* emb = dec ? eB : eA;
    const float* Wih = dec ? WB : WA;
    const float* bih = dec ? bB : bA;
    const int*  toks = dec ? tB : tA;
    float* Gi        = dec ? GiB : GiA;

    __shared__ __align__(16) float As[GI_BK * GI_BM];
    __shared__ __align__(16) float Bs[GI_BK * GI_BN];
    const int tid = threadIdx.x;
    const int n0 = blockIdx.x * GI_BN;
    const int m0 = blockIdx.y * GI_BM;
    const int tx = tid & 15, ty = tid >> 4;
    float acc[4][4] = {};
    for (int k0 = 0; k0 < H; k0 += GI_BK) {
        for (int x = tid; x < 320; x += 256) {        // 64 rows x 5 float4
            int m = x / 5, kq = x - m * 5;
            int gm = m0 + m;
            int tok = dec ? ((gm == 0) ? 0 : toks[gm - 1]) : toks[gm];
            float4 v = *(const float4*)(emb + (size_t)tok * H + k0 + kq * 4);
            if (dec) { v.x = fmaxf(v.x, 0.f); v.y = fmaxf(v.y, 0.f);
                       v.z = fmaxf(v.z, 0.f); v.w = fmaxf(v.w, 0.f); }
            int kb = kq * 4;
            As[(kb + 0) * GI_BM + m] = v.x; As[(kb + 1) * GI_BM + m] = v.y;
            As[(kb + 2) * GI_BM + m] = v.z; As[(kb + 3) * GI_BM + m] = v.w;
        }
        for (int x = tid; x < 320; x += 256) {
            int n = x / 5, kq = x - n * 5;
            int gn = n0 + n;
            float4 v = make_float4(0.f, 0.f, 0.f, 0.f);
            if (gn < G3) v = *(const float4*)(Wih + (size_t)gn * H + k0 + kq * 4);
            int kb = kq * 4;
            Bs[(kb + 0) * GI_BN + n] = v.x; Bs[(kb + 1) * GI_BN + n] = v.y;
            Bs[(kb + 2) * GI_BN + n] = v.z; Bs[(kb + 3) * GI_BN + n] = v.w;
        }
        __syncthreads();
#pragma unroll 5
        for (int kk = 0; kk < GI_BK; ++kk) {
            float a[4], b[4];
            *(float4*)&a[0] = *(const float4*)&As[kk * GI_BM + ty * 4];
            *(float4*)&b[0] = *(const float4*)&Bs[kk * GI_BN + tx * 4];
#pragma unroll
            for (int i = 0; i < 4; i++)
#pragma unroll
                for (int j = 0; j < 4; j++) acc[i][j] = fmaf(a[i], b[j], acc[i][j]);
        }
        __syncthreads();
    }
#pragma unroll
    for (int i = 0; i < 4; i++) {
        int gm = m0 + ty * 4 + i;
#pragma unroll
        for (int j = 0; j < 4; j++) {
            int gn = n0 + tx * 4 + j;
            if (gn < G3) Gi[(size_t)gm * G3 + gn] = acc[i][j] + bih[gn];
        }
    }
}

// ---------------- persistent GRU scan: tagged-pair dataflow ----------------
// Poll: lane tid<250 spins on ONLY its 2 pairs (2*tid, 2*tid+1) -> LDS h_s[500].
// FMA: g=tid/25 (6 rows), s=tid%25 (k-segment of 20), W held in 120 VGPRs/lane.
__global__ __launch_bounds__(256, 1) void k_gru(
    const float* __restrict__ Whh, const float* __restrict__ bhh,
    const float* __restrict__ Gi, const float* __restrict__ h0,
    unsigned long long* hbuf, float* hfinal, float* hs_out, float* douth, int S)
{
    __shared__ __align__(16) float h_s[H];
    __shared__ float p_s[ROWS * 26];   // partials, stride 26 breaks bank conflicts
    __shared__ float gh_s[ROWS];
    const int tid = threadIdx.x;
    const int wg = blockIdx.x;
    const int j0 = wg * HSL;

    const int g = tid / 25;            // 0..9  (tid<250)
    const int s = tid - g * 25;        // 0..24
    // poll assignment: pairs 2*tid, 2*tid+1 -> slice tid/10, elems 2*(tid%10), +1
    const int slc = tid / 10;
    const int e0  = 2 * (tid - slc * 10);

    // ---- preload W rows into registers (120 VGPRs/lane) ----
    float wreg[6][20];
    if (tid < 250) {
#pragma unroll
        for (int r = 0; r < 6; ++r) {
            const int rl = g * 6 + r;                    // 0..59
            const int gate = rl / 20, jl = rl - gate * 20;
            const float* wr = Whh + (size_t)(gate * 500 + j0 + jl) * H + s * 20;
#pragma unroll
            for (int c = 0; c < 5; ++c)
                *(float4*)&wreg[r][c * 4] = *(const float4*)(wr + c * 4);
        }
    }
    float bb = 0.f;
    if (tid < ROWS) {
        const int gate = tid / 20, jl = tid - gate * 20;
        bb = bhh[gate * 500 + j0 + jl];
    }
    // own h slice lives in a register of lanes tid<HSL
    float hown = (tid < HSL) ? h0[j0 + tid] : 0.f;

    // ---- prestage h0 into buf1 with tag 1 ----
    if (tid < HSL)
        __hip_atomic_store(hbuf + 800 + wg * 32 + tid,
                           ((unsigned long long)1u << 32) | (unsigned)__float_as_uint(hown),
                           __ATOMIC_RELAXED, __HIP_MEMORY_SCOPE_AGENT);

    for (int t = 0; t < S; ++t) {
        const unsigned want = (unsigned)(t + 1);
        const int rb = (t + 1) & 1;                      // read buffer
        // Gi prefetch (long-latency, overlaps the poll)
        float ir = 0.f, iz = 0.f, inn = 0.f;
        if (tid < HSL) {
            const float* gi = Gi + (size_t)t * G3 + j0 + tid;
            ir = gi[0]; iz = gi[500]; inn = gi[1000];
        }
        // ---- poll own 2 pairs until tags match, then publish to LDS ----
        if (tid < 250) {
            const unsigned long long* pa = hbuf + rb * 800 + slc * 32 + e0;
            unsigned long long v0, v1;
            do {
                v0 = __hip_atomic_load(pa,     __ATOMIC_RELAXED, __HIP_MEMORY_SCOPE_AGENT);
                v1 = __hip_atomic_load(pa + 1, __ATOMIC_RELAXED, __HIP_MEMORY_SCOPE_AGENT);
            } while (((unsigned)(v0 >> 32) != want) || ((unsigned)(v1 >> 32) != want));
            h_s[2 * tid]     = __uint_as_float((unsigned)v0);
            h_s[2 * tid + 1] = __uint_as_float((unsigned)v1);
        }
        __syncthreads();
        // ---- dot: 120 FMAs, W from registers, h from LDS ----
        if (tid < 250) {
            float hv[20];
#pragma unroll
            for (int c = 0; c < 5; ++c)
                *(float4*)&hv[c * 4] = *(const float4*)&h_s[s * 20 + c * 4];
            float acc[6] = {0.f, 0.f, 0.f, 0.f, 0.f, 0.f};
#pragma unroll
            for (int i = 0; i < 20; ++i)
#pragma unroll
                for (int r = 0; r < 6; ++r) acc[r] = fmaf(wreg[r][i], hv[i], acc[r]);
#pragma unroll
            for (int r = 0; r < 6; ++r) p_s[(g * 6 + r) * 26 + s] = acc[r];
        }
        __syncthreads();
        // ---- row reduction over the 25 k-segments ----
        if (tid < ROWS) {
            float sum = 0.f;
#pragma unroll 5
            for (int i = 0; i < 25; ++i) sum += p_s[tid * 26 + i];
            gh_s[tid] = sum + bb;
        }
        __syncthreads();
        // ---- GRU update for own slice ----
        if (tid < HSL) {
            const int j = j0 + tid;
            const float hr = gh_s[tid], hz = gh_s[HSL + tid], hn = gh_s[2 * HSL + tid];
            const float r = 1.f / (1.f + __expf(-(ir + hr)));
            const float z = 1.f / (1.f + __expf(-(iz + hz)));
            const float n = tanhf(inn + r * hn);
            const float hnew = (1.f - z) * n + z * hown;
            hown = hnew;
            __hip_atomic_store(hbuf + (t & 1) * 800 + wg * 32 + tid,
                               ((unsigned long long)(unsigned)(t + 2) << 32) |
                               (unsigned)__float_as_uint(hnew),
                               __ATOMIC_RELAXED, __HIP_MEMORY_SCOPE_AGENT);
            if (hs_out) hs_out[(size_t)t * H + j] = hnew;
            if (t == S - 1) {
                if (hfinal) hfinal[j] = hnew;
                if (douth)  douth[j]  = hnew;
            }
        }
        // h_s rewrite next iter is safe: writers passed B2 (all h_s readers done)
    }
}

// ---------------- logits GEMM with fused sum-exp / argmax partials ----------------
#define LG_BM 128
#define LG_BN 128
#define LG_BK 20
__global__ __launch_bounds__(256) void k_logits(
    const float* __restrict__ A, const float* __restrict__ Bw,
    const float* __restrict__ bias,
    float* __restrict__ S_part, unsigned long long* __restrict__ P_part)
{
    __shared__ __align__(16) float As[LG_BK * LG_BM];
    __shared__ __align__(16) float Bs[LG_BK * LG_BN];
    const int tid = threadIdx.x;
    const int bx = blockIdx.x;
    const int n0 = bx * LG_BN;
    const int m0 = blockIdx.y * LG_BM;
    const int tx = tid & 15, ty = tid >> 4;
    float acc[8][8] = {};
    for (int k0 = 0; k0 < H; k0 += LG_BK) {
        for (int x = tid; x < LG_BM * LG_BK; x += 256) {
            int m = x / LG_BK, k = x - m * LG_BK;
            As[k * LG_BM + m] = A[(size_t)(m0 + m) * H + k0 + k];
        }
        for (int x = tid; x < LG_BN * LG_BK; x += 256) {
            int n = x / LG_BK, k = x - n * LG_BK;
            int gn = n0 + n;
            Bs[k * LG_BN + n] = (gn < V) ? Bw[(size_t)gn * H + k0 + k] : 0.f;
        }
        __syncthreads();
#pragma unroll 5
        for (int kk = 0; kk < LG_BK; ++kk) {
            float a[8], b[8];
            *(float4*)&a[0] = *(const float4*)&As[kk * LG_BM + ty * 8];
            *(float4*)&a[4] = *(const float4*)&As[kk * LG_BM + ty * 8 + 4];
            *(float4*)&b[0] = *(const float4*)&Bs[kk * LG_BN + tx * 8];
            *(float4*)&b[4] = *(const float4*)&Bs[kk * LG_BN + tx * 8 + 4];
#pragma unroll
            for (int i = 0; i < 8; i++)
#pragma unroll
                for (int j = 0; j < 8; j++) acc[i][j] = fmaf(a[i], b[j], acc[i][j]);
        }
        __syncthreads();
    }
    float bcol[8]; int gncol[8]; bool bval[8];
#pragma unroll
    for (int j = 0; j < 8; j++) {
        int gn = n0 + tx * 8 + j;
        gncol[j] = gn; bval[j] = gn < V; bcol[j] = bval[j] ? bias[gn] : 0.f;
    }
#pragma unroll
    for (int i = 0; i < 8; i++) {
        int gm = m0 + ty * 8 + i;
        float mx = -3.4e38f; unsigned mi = 0; float se = 0.f;
#pragma unroll
        for (int j = 0; j < 8; j++) {
            if (bval[j]) {
                float l = acc[i][j] + bcol[j];
                se += __expf(l);
                if (l > mx) { mx = l; mi = (unsigned)gncol[j]; }
            }
        }
        unsigned u = __float_as_uint(mx);
        unsigned key = (u & 0x80000000u) ? ~u : (u | 0x80000000u);
        unsigned long long pk = ((unsigned long long)key << 32) |
                                (unsigned long long)(0xFFFFFFFFu - mi);
#pragma unroll
        for (int off = 1; off < 16; off <<= 1) {
            unsigned long long pk2 = __shfl_xor(pk, off);
            se += __shfl_xor(se, off);
            if (pk2 > pk) pk = pk2;
        }
        if (tx == 0) {
            S_part[(size_t)gm * NT + bx] = se;
            P_part[(size_t)gm * NT + bx] = pk;
        }
    }
}

__global__ __launch_bounds__(128) void k_reduce_rows(
    const float* __restrict__ S_part, const unsigned long long* __restrict__ P_part,
    float* __restrict__ Sfin, float* __restrict__ out_argmax)
{
    const int row = blockIdx.x, tid = threadIdx.x;
    float s = 0.f; unsigned long long p = 0ull;
    for (int i = tid; i < NT; i += 128) {
        s += S_part[(size_t)row * NT + i];
        unsigned long long q = P_part[(size_t)row * NT + i];
        if (q > p) p = q;
    }
#pragma unroll
    for (int off = 1; off < 64; off <<= 1) {
        s += __shfl_xor(s, off);
        unsigned long long q = __shfl_xor(p, off);
        if (q > p) p = q;
    }
    __shared__ float s2[2];
    __shared__ unsigned long long p2[2];
    if ((tid & 63) == 0) { s2[tid >> 6] = s; p2[tid >> 6] = p; }
    __syncthreads();
    if (tid == 0) {
        s = s2[0] + s2[1];
        p = p2[0] > p2[1] ? p2[0] : p2[1];
        Sfin[row] = s;
        unsigned idx = 0xFFFFFFFFu - (unsigned)(p & 0xFFFFFFFFull);
        out_argmax[row] = (float)idx;
    }
}

__global__ __launch_bounds__(64) void k_ltgt(
    const float* __restrict__ A, const float* __restrict__ Bw,
    const float* __restrict__ bias, const int* __restrict__ tgt,
    float* __restrict__ ltgt)
{
    const int row = blockIdx.x, lane = threadIdx.x;
    const int tok = tgt[row];
    const float* a = A + (size_t)row * H;
    const float* b = Bw + (size_t)tok * H;
    float s = 0.f;
    for (int k = lane; k < H; k += 64) s = fmaf(a[k], b[k], s);
#pragma unroll
    for (int off = 1; off < 64; off <<= 1) s += __shfl_xor(s, off);
    if (lane == 0) ltgt[row] = s + bias[tok];
}

__global__ __launch_bounds__(512) void k_final(
    const float* __restrict__ Sfin, const float* __restrict__ ltgt, float* __restrict__ d_out)
{
    __shared__ float red[512];
    const int t = threadIdx.x;
    red[t] = logf(Sfin[t]) - ltgt[t];
    __syncthreads();
    for (int s = 256; s > 0; s >>= 1) {
        if (t < s) red[t] += red[t + s];
        __syncthreads();
    }
    if (t == 0) d_out[0] = red[0];
}

extern "C" void kernel_launch(void* const* d_in, const int* in_sizes, int n_in,
                              void* d_out, int out_size, void* d_ws, size_t ws_size,
                              hipStream_t stream) {
    const int*   enc_ids = (const int*)d_in[0];
    const int*   tgt     = (const int*)d_in[1];
    const float* enc_h0  = (const float*)d_in[2];
    const float* enc_emb = (const float*)d_in[3];
    const float* enc_Wih = (const float*)d_in[4];
    const float* enc_Whh = (const float*)d_in[5];
    const float* enc_bih = (const float*)d_in[6];
    const float* enc_bhh = (const float*)d_in[7];
    const float* dec_emb = (const float*)d_in[8];
    const float* dec_Wih = (const float*)d_in[9];
    const float* dec_Whh = (const float*)d_in[10];
    const float* dec_bih = (const float*)d_in[11];
    const float* dec_bhh = (const float*)d_in[12];
    const float* out_W   = (const float*)d_in[13];
    const float* out_b   = (const float*)d_in[14];
    float* out = (float*)d_out;

    char* ws = (char*)d_ws;
    unsigned long long* hbufE = (unsigned long long*)(ws + OFS_HBUF_E);
    unsigned long long* hbufD = (unsigned long long*)(ws + OFS_HBUF_D);
    float* ench   = (float*)(ws + OFS_ENCH);
    float* gi_enc = (float*)(ws + OFS_GI_ENC);
    float* gi_dec = (float*)(ws + OFS_GI_DEC);
    float* dechs  = (float*)(ws + OFS_DECHS);
    float* Spart  = (float*)(ws + OFS_SPART);
    unsigned long long* Ppart = (unsigned long long*)(ws + OFS_PPART);
    float* ltgt   = (float*)(ws + OFS_LTGT);
    float* Sfin   = (float*)(ws + OFS_SFIN);

    k_gi_gemm<<<dim3(24, 8, 2), dim3(256), 0, stream>>>(
        enc_emb, enc_Wih, enc_bih, enc_ids,
        dec_emb, dec_Wih, dec_bih, tgt, gi_enc, gi_dec);
    k_gru<<<dim3(NB), dim3(256), 0, stream>>>(enc_Whh, enc_bhh, gi_enc, enc_h0,
                                              hbufE, ench, (float*)nullptr, out + 1, SEQ);
    k_gru<<<dim3(NB), dim3(256), 0, stream>>>(dec_Whh, dec_bhh, gi_dec, ench,
                                              hbufD, (float*)nullptr, dechs, (float*)nullptr, SEQ);
    k_ltgt<<<dim3(SEQ), dim3(64), 0, stream>>>(dechs, out_W, out_b, tgt, ltgt);
    k_logits<<<dim3(NT, 4), dim3(256), 0, stream>>>(dechs, out_W, out_b, Spart, Ppart);
    k_reduce_rows<<<dim3(SEQ), dim3(128), 0, stream>>>(Spart, Ppart, Sfin, out + 1 + H);
    k_final<<<dim3(1), dim3(512), 0, stream>>>(Sfin, ltgt, out);
}